// Round 2
// baseline (604.091 us; speedup 1.0000x reference)
//
#include <hip/hip_runtime.h>
#include <hip/hip_bf16.h>
#include <cstdint>

// ---------------------------------------------------------------------------
// MultiHeadAttention (B=4, L=2048, d_model=1024, 16 heads, d_k=d_v=64)
//   qh = q @ Wq, kh = q @ Wk, vh = q @ Wv   (per head)
//   attn = softmax(qh kh^T / 32) vh
//   z = concat(attn) @ proj_w^T + proj_b + q ; out = LN(z) (ddof=1, /(sigma+eps))
// Inputs/outputs fp32 (per reference). Internally: bf16 MFMA, fp32 accum.
// ---------------------------------------------------------------------------

typedef __attribute__((ext_vector_type(8))) short   short8;
typedef __attribute__((ext_vector_type(8))) __bf16  bf16x8;
typedef __attribute__((ext_vector_type(4))) float   float4v;

// mfma shim: works whether the builtin signature is short8 or bf16x8.
template <typename V>
__device__ __forceinline__ auto mfma_sel(V a, V b, float4v c, int)
    -> decltype(__builtin_amdgcn_mfma_f32_16x16x32_bf16(a, b, c, 0, 0, 0)) {
  return __builtin_amdgcn_mfma_f32_16x16x32_bf16(a, b, c, 0, 0, 0);
}
template <typename V>
__device__ __forceinline__ float4v mfma_sel(V a, V b, float4v c, long) {
  return __builtin_amdgcn_mfma_f32_16x16x32_bf16(
      __builtin_bit_cast(bf16x8, a), __builtin_bit_cast(bf16x8, b), c, 0, 0, 0);
}
__device__ __forceinline__ float4v MFMA(short8 a, short8 b, float4v c) {
  return mfma_sel(a, b, c, 0);
}

__device__ __forceinline__ unsigned short f2b(float f) {
  union { float f; unsigned int u; } x; x.f = f;
  unsigned int r = x.u + 0x7FFFu + ((x.u >> 16) & 1u);  // RNE
  return (unsigned short)(r >> 16);
}

constexpr int Bb = 4, Ls = 2048, Dm = 1024, NH = 16;
constexpr int Mrows = Bb * Ls;          // 8192
constexpr int NQKV = 3 * Dm;            // 3072
constexpr int NQ_ELEMS = Mrows * Dm;    // 8388608
constexpr int NP_ELEMS = Dm * Dm;       // 1048576

// --- fp32 -> bf16 conversion for q (8M) and proj_w (1M)
__global__ __launch_bounds__(256) void conv_kernel(const float* __restrict__ q,
                                                   const float* __restrict__ pw,
                                                   unsigned short* __restrict__ Qb,
                                                   unsigned short* __restrict__ Pb) {
  int idx = blockIdx.x * 256 + threadIdx.x;  // 9437184 total
  if (idx < NQ_ELEMS) Qb[idx] = f2b(q[idx]);
  else                Pb[idx - NQ_ELEMS] = f2b(pw[idx - NQ_ELEMS]);
}

// --- repack fp32 w_qs/w_ks/w_vs [16][1024][64] -> bf16 Wt[3072][1024]
__global__ __launch_bounds__(256) void repack_w(const float* __restrict__ wq,
                                                const float* __restrict__ wk,
                                                const float* __restrict__ wv,
                                                unsigned short* __restrict__ Wt) {
  int idx = blockIdx.x * 256 + threadIdx.x;      // 3*1024*1024 total
  int n = idx >> 10, d = idx & 1023;
  const float* w = (n < 1024) ? wq : (n < 2048 ? wk : wv);
  int nn = n & 1023;
  int h = nn >> 6, kk = nn & 63;
  Wt[idx] = f2b(w[(h * 1024 + d) * 64 + kk]);
}

// --- C = A[M][K] * Bt[N][K]^T (bf16 in), 128x128 tile, BK=32, 4 waves 64x64
// MODE 0: store bf16 to Cb.  MODE 1: +bias(f32) +residual(f32), store fp32 Cf.
template <int MODE>
__global__ __launch_bounds__(256) void gemm_bt(const unsigned short* __restrict__ A,
                                               const unsigned short* __restrict__ Bt,
                                               unsigned short* __restrict__ Cb,
                                               float* __restrict__ Cf,
                                               const float* __restrict__ bias,
                                               const float* __restrict__ resid,
                                               int N, int K) {
  __shared__ __align__(16) unsigned short As[128 * 32];
  __shared__ __align__(16) unsigned short Bs[128 * 32];
  const int tid = threadIdx.x;
  const int lane = tid & 63, w = tid >> 6;
  const int wm = (w >> 1) * 64, wn = (w & 1) * 64;
  const int m0 = blockIdx.y * 128, n0 = blockIdx.x * 128;
  const int r = lane & 15, q = lane >> 4;

  float4v acc[4][4] = {};

  for (int k0 = 0; k0 < K; k0 += 32) {
#pragma unroll
    for (int rep = 0; rep < 2; ++rep) {
      int c = tid + rep * 256;               // 512 chunks of 8 bf16
      int row = c >> 2, col = (c & 3) * 8;
      *(uint4*)&As[row * 32 + col] = *(const uint4*)&A[(size_t)(m0 + row) * K + k0 + col];
      *(uint4*)&Bs[row * 32 + col] = *(const uint4*)&Bt[(size_t)(n0 + row) * K + k0 + col];
    }
    __syncthreads();
    short8 af[4], bfr[4];
#pragma unroll
    for (int i = 0; i < 4; ++i)
      af[i] = *(const short8*)&As[(wm + i * 16 + r) * 32 + q * 8];
#pragma unroll
    for (int j = 0; j < 4; ++j)
      bfr[j] = *(const short8*)&Bs[(wn + j * 16 + r) * 32 + q * 8];
#pragma unroll
    for (int i = 0; i < 4; ++i)
#pragma unroll
      for (int j = 0; j < 4; ++j)
        acc[i][j] = MFMA(af[i], bfr[j], acc[i][j]);
    __syncthreads();
  }

#pragma unroll
  for (int i = 0; i < 4; ++i)
#pragma unroll
    for (int j = 0; j < 4; ++j)
#pragma unroll
      for (int rg = 0; rg < 4; ++rg) {
        int row = m0 + wm + i * 16 + q * 4 + rg;
        int col = n0 + wn + j * 16 + r;
        float v = acc[i][j][rg];
        if (MODE == 0) {
          Cb[(size_t)row * N + col] = f2b(v);
        } else {
          v += bias[col] + resid[(size_t)row * N + col];
          Cf[(size_t)row * N + col] = v;
        }
      }
}

// --- flash attention: one block = (h, b, 64 q-rows). QKV[8192][3072]:
// cols [0,1024)=Q, [1024,2048)=K, [2048,3072)=V, each head-major h*64+d.
__global__ __launch_bounds__(256) void attn_kernel(const unsigned short* __restrict__ QKV,
                                                   unsigned short* __restrict__ O) {
  const int bx = blockIdx.x;
  const int qt = bx & 31, hb = bx >> 5;
  const int h = hb & 15, b = hb >> 4;
  const int tid = threadIdx.x, lane = tid & 63, w = tid >> 6;
  const int r = lane & 15, q = lane >> 4;

  __shared__ __align__(16) unsigned short Ks[64 * 64];    // [key][d]
  __shared__ __align__(16) unsigned short Vst[64 * 64];   // [dv][key] (transposed)
  __shared__ __align__(16) unsigned short Ps[4 * 16 * 64];// per-wave P round-trip

  const size_t RS = 3072;
  const int l0 = qt * 64;

  short8 aq[2];
  {
    const unsigned short* Qr = QKV + (size_t)(b * 2048 + l0 + w * 16 + r) * RS + h * 64;
    aq[0] = *(const short8*)&Qr[q * 8];
    aq[1] = *(const short8*)&Qr[32 + q * 8];
  }

  float4v oacc[4] = {};
  float mrow[4], lrow[4];
#pragma unroll
  for (int i = 0; i < 4; ++i) { mrow[i] = -1e30f; lrow[i] = 0.f; }

  for (int kt = 0; kt < 2048; kt += 64) {
    __syncthreads();
    // stage K tile [64][64]
#pragma unroll
    for (int rep = 0; rep < 2; ++rep) {
      int c = tid + rep * 256;
      int row = c >> 3, off = (c & 7) * 8;
      *(uint4*)&Ks[row * 64 + off] =
          *(const uint4*)&QKV[(size_t)(b * 2048 + kt + row) * RS + 1024 + h * 64 + off];
    }
    // stage V tile transposed -> Vst[dv][key]
#pragma unroll
    for (int rep = 0; rep < 2; ++rep) {
      int c = tid + rep * 256;
      int key = c >> 3, dv0 = (c & 7) * 8;
      uint4 raw = *(const uint4*)&QKV[(size_t)(b * 2048 + kt + key) * RS + 2048 + h * 64 + dv0];
      unsigned short tmp[8];
      *(uint4*)tmp = raw;
#pragma unroll
      for (int i = 0; i < 8; ++i) Vst[(dv0 + i) * 64 + key] = tmp[i];
    }
    __syncthreads();

    // S = (Q K^T) / 32 for this wave's 16 q-rows x 64 keys
    float4v sacc[4];
#pragma unroll
    for (int jn = 0; jn < 4; ++jn) {
      short8 bk0 = *(const short8*)&Ks[(jn * 16 + r) * 64 + q * 8];
      short8 bk1 = *(const short8*)&Ks[(jn * 16 + r) * 64 + 32 + q * 8];
      float4v z = {0.f, 0.f, 0.f, 0.f};
      z = MFMA(aq[0], bk0, z);
      z = MFMA(aq[1], bk1, z);
#pragma unroll
      for (int rg = 0; rg < 4; ++rg) z[rg] *= 0.03125f;
      sacc[jn] = z;
    }

    // online softmax per q-row (row = q*4+rg; 64 cols across 16 lanes x 4 jn)
#pragma unroll
    for (int rg = 0; rg < 4; ++rg) {
      float mx = -1e30f;
#pragma unroll
      for (int jn = 0; jn < 4; ++jn) mx = fmaxf(mx, sacc[jn][rg]);
#pragma unroll
      for (int d = 1; d < 16; d <<= 1) mx = fmaxf(mx, __shfl_xor(mx, d));
      float m_new = fmaxf(mrow[rg], mx);
      float alpha = __expf(mrow[rg] - m_new);
      mrow[rg] = m_new;
      float rs = 0.f;
#pragma unroll
      for (int jn = 0; jn < 4; ++jn) {
        float p = __expf(sacc[jn][rg] - m_new);
        sacc[jn][rg] = p;
        rs += p;
      }
#pragma unroll
      for (int d = 1; d < 16; d <<= 1) rs += __shfl_xor(rs, d);
      lrow[rg] = lrow[rg] * alpha + rs;
#pragma unroll
      for (int jv = 0; jv < 4; ++jv) oacc[jv][rg] *= alpha;
    }

    // P (C-layout) -> LDS -> A-layout (wave-private, no barrier needed)
#pragma unroll
    for (int jn = 0; jn < 4; ++jn)
#pragma unroll
      for (int rg = 0; rg < 4; ++rg)
        Ps[(w * 16 + q * 4 + rg) * 64 + jn * 16 + r] = f2b(sacc[jn][rg]);
    short8 ap0 = *(const short8*)&Ps[(w * 16 + r) * 64 + q * 8];
    short8 ap1 = *(const short8*)&Ps[(w * 16 + r) * 64 + 32 + q * 8];

    // O += P V
#pragma unroll
    for (int jv = 0; jv < 4; ++jv) {
      short8 bv0 = *(const short8*)&Vst[(jv * 16 + r) * 64 + q * 8];
      short8 bv1 = *(const short8*)&Vst[(jv * 16 + r) * 64 + 32 + q * 8];
      oacc[jv] = MFMA(ap0, bv0, oacc[jv]);
      oacc[jv] = MFMA(ap1, bv1, oacc[jv]);
    }
  }

#pragma unroll
  for (int jv = 0; jv < 4; ++jv)
#pragma unroll
    for (int rg = 0; rg < 4; ++rg) {
      int row = b * 2048 + l0 + w * 16 + q * 4 + rg;
      int col = h * 64 + jv * 16 + r;
      O[(size_t)row * 1024 + col] = f2b(oacc[jv][rg] / lrow[rg]);
    }
}

// --- row LayerNorm: mean, std(ddof=1), /(sigma+1e-3)*a + b  (all fp32)
__global__ __launch_bounds__(256) void ln_kernel(const float* __restrict__ Z,
                                                 const float* __restrict__ ga,
                                                 const float* __restrict__ be,
                                                 float* __restrict__ out) {
  const int row = blockIdx.x;
  const float* z = Z + (size_t)row * 1024;
  const int tid = threadIdx.x;
  float v[4], s = 0.f, sq = 0.f;
#pragma unroll
  for (int i = 0; i < 4; ++i) {
    v[i] = z[tid + i * 256];
    s += v[i];
    sq += v[i] * v[i];
  }
#pragma unroll
  for (int d = 1; d < 64; d <<= 1) { s += __shfl_xor(s, d); sq += __shfl_xor(sq, d); }
  __shared__ float ss[4], ssq[4];
  const int w = tid >> 6, lane = tid & 63;
  if (lane == 0) { ss[w] = s; ssq[w] = sq; }
  __syncthreads();
  s = ss[0] + ss[1] + ss[2] + ss[3];
  sq = ssq[0] + ssq[1] + ssq[2] + ssq[3];
  float mu = s * (1.f / 1024.f);
  float var = fmaxf((sq - 1024.f * mu * mu) * (1.f / 1023.f), 0.f);
  float inv = 1.f / (sqrtf(var) + 1e-3f);
#pragma unroll
  for (int i = 0; i < 4; ++i) {
    int c = tid + i * 256;
    out[(size_t)row * 1024 + c] = (v[i] - mu) * inv * ga[c] + be[c];
  }
}

extern "C" void kernel_launch(void* const* d_in, const int* in_sizes, int n_in,
                              void* d_out, int out_size, void* d_ws, size_t ws_size,
                              hipStream_t stream) {
  (void)in_sizes; (void)n_in; (void)out_size; (void)ws_size;
  const float* q      = (const float*)d_in[0];
  const float* w_qs   = (const float*)d_in[1];
  const float* w_ks   = (const float*)d_in[2];
  const float* w_vs   = (const float*)d_in[3];
  const float* proj_w = (const float*)d_in[4];
  const float* proj_b = (const float*)d_in[5];
  const float* ln_a   = (const float*)d_in[6];
  const float* ln_b   = (const float*)d_in[7];
  float* out = (float*)d_out;

  // ws layout (88 MB): [Qb 16MB][O 16MB][QKV 48MB][Wt 6MB][Pb 2MB]
  // Z (fp32, 32MB) aliases QKV (dead after attention).
  unsigned short* Qb  = (unsigned short*)d_ws;
  unsigned short* O   = Qb + (size_t)Mrows * Dm;
  unsigned short* QKV = O + (size_t)Mrows * Dm;
  unsigned short* Wt  = QKV + (size_t)Mrows * NQKV;
  unsigned short* Pb  = Wt + (size_t)NQKV * Dm;
  float* Z = (float*)QKV;

  conv_kernel<<<dim3((NQ_ELEMS + NP_ELEMS) / 256), dim3(256), 0, stream>>>(q, proj_w, Qb, Pb);
  repack_w<<<dim3((3 * 1024 * 1024) / 256), dim3(256), 0, stream>>>(w_qs, w_ks, w_vs, Wt);
  gemm_bt<0><<<dim3(NQKV / 128, Mrows / 128), dim3(256), 0, stream>>>(
      Qb, Wt, QKV, nullptr, nullptr, nullptr, NQKV, Dm);
  attn_kernel<<<dim3(32 * NH * Bb), dim3(256), 0, stream>>>(QKV, O);
  gemm_bt<1><<<dim3(Dm / 128, Mrows / 128), dim3(256), 0, stream>>>(
      O, Pb, nullptr, Z, proj_b, q, Dm, Dm);
  ln_kernel<<<dim3(Mrows), dim3(256), 0, stream>>>(Z, ln_a, ln_b, out);
}

// Round 3
// 456.406 us; speedup vs baseline: 1.3236x; 1.3236x over previous
//
#include <hip/hip_runtime.h>
#include <hip/hip_bf16.h>
#include <cstdint>

// ---------------------------------------------------------------------------
// MultiHeadAttention (B=4, L=2048, d_model=1024, 16 heads, d_k=d_v=64)
// Inputs/outputs fp32. Internals: bf16 MFMA, fp32 accum.
// R2: V written pre-transposed by QKV-GEMM epilogue (kills 16-way LDS
//     conflicts in attention); all attn LDS tiles padded to stride 72.
// ---------------------------------------------------------------------------

typedef __attribute__((ext_vector_type(8))) short   short8;
typedef __attribute__((ext_vector_type(8))) __bf16  bf16x8;
typedef __attribute__((ext_vector_type(4))) float   float4v;

template <typename V>
__device__ __forceinline__ auto mfma_sel(V a, V b, float4v c, int)
    -> decltype(__builtin_amdgcn_mfma_f32_16x16x32_bf16(a, b, c, 0, 0, 0)) {
  return __builtin_amdgcn_mfma_f32_16x16x32_bf16(a, b, c, 0, 0, 0);
}
template <typename V>
__device__ __forceinline__ float4v mfma_sel(V a, V b, float4v c, long) {
  return __builtin_amdgcn_mfma_f32_16x16x32_bf16(
      __builtin_bit_cast(bf16x8, a), __builtin_bit_cast(bf16x8, b), c, 0, 0, 0);
}
__device__ __forceinline__ float4v MFMA(short8 a, short8 b, float4v c) {
  return mfma_sel(a, b, c, 0);
}

__device__ __forceinline__ unsigned short f2b(float f) {
  union { float f; unsigned int u; } x; x.f = f;
  unsigned int r = x.u + 0x7FFFu + ((x.u >> 16) & 1u);  // RNE
  return (unsigned short)(r >> 16);
}

constexpr int Bb = 4, Ls = 2048, Dm = 1024, NH = 16;
constexpr int Mrows = Bb * Ls;          // 8192
constexpr int NQKV = 3 * Dm;            // 3072
constexpr int NQ_ELEMS = Mrows * Dm;    // 8388608
constexpr int NP_ELEMS = Dm * Dm;       // 1048576
constexpr int PAD = 72;                 // LDS row stride (halfwords), 144B

// --- fp32 -> bf16 conversion for q (8M) and proj_w (1M)
__global__ __launch_bounds__(256) void conv_kernel(const float* __restrict__ q,
                                                   const float* __restrict__ pw,
                                                   unsigned short* __restrict__ Qb,
                                                   unsigned short* __restrict__ Pb) {
  int idx = blockIdx.x * 256 + threadIdx.x;  // 9437184 total
  if (idx < NQ_ELEMS) Qb[idx] = f2b(q[idx]);
  else                Pb[idx - NQ_ELEMS] = f2b(pw[idx - NQ_ELEMS]);
}

// --- repack fp32 w_qs/w_ks/w_vs [16][1024][64] -> bf16 Wt[3072][1024]
__global__ __launch_bounds__(256) void repack_w(const float* __restrict__ wq,
                                                const float* __restrict__ wk,
                                                const float* __restrict__ wv,
                                                unsigned short* __restrict__ Wt) {
  int idx = blockIdx.x * 256 + threadIdx.x;      // 3*1024*1024 total
  int n = idx >> 10, d = idx & 1023;
  const float* w = (n < 1024) ? wq : (n < 2048 ? wk : wv);
  int nn = n & 1023;
  int h = nn >> 6, kk = nn & 63;
  Wt[idx] = f2b(w[(h * 1024 + d) * 64 + kk]);
}

// --- C = A[M][K] * Bt[N][K]^T (bf16), 128x128 tile, BK=32, 4 waves 64x64
// MODE 0 (QKV): cols<2048 -> QK[row*2048+col] bf16; cols>=2048 -> V
//   transposed into Vt[col-2048][row] (uint2 of 4 contiguous rows).
// MODE 1 (proj): +bias(f32) +residual(f32), store fp32 Cf[row*N+col].
template <int MODE>
__global__ __launch_bounds__(256) void gemm_bt(const unsigned short* __restrict__ A,
                                               const unsigned short* __restrict__ Bt,
                                               unsigned short* __restrict__ QK,
                                               unsigned short* __restrict__ Vt,
                                               float* __restrict__ Cf,
                                               const float* __restrict__ bias,
                                               const float* __restrict__ resid,
                                               int N, int K) {
  __shared__ __align__(16) unsigned short As[128 * 32];
  __shared__ __align__(16) unsigned short Bs[128 * 32];
  const int tid = threadIdx.x;
  const int lane = tid & 63, w = tid >> 6;
  const int wm = (w >> 1) * 64, wn = (w & 1) * 64;
  const int m0 = blockIdx.y * 128, n0 = blockIdx.x * 128;
  const int r = lane & 15, q = lane >> 4;

  float4v acc[4][4] = {};

  for (int k0 = 0; k0 < K; k0 += 32) {
#pragma unroll
    for (int rep = 0; rep < 2; ++rep) {
      int c = tid + rep * 256;               // 512 chunks of 8 bf16
      int row = c >> 2, col = (c & 3) * 8;
      *(uint4*)&As[row * 32 + col] = *(const uint4*)&A[(size_t)(m0 + row) * K + k0 + col];
      *(uint4*)&Bs[row * 32 + col] = *(const uint4*)&Bt[(size_t)(n0 + row) * K + k0 + col];
    }
    __syncthreads();
    short8 af[4], bfr[4];
#pragma unroll
    for (int i = 0; i < 4; ++i)
      af[i] = *(const short8*)&As[(wm + i * 16 + r) * 32 + q * 8];
#pragma unroll
    for (int j = 0; j < 4; ++j)
      bfr[j] = *(const short8*)&Bs[(wn + j * 16 + r) * 32 + q * 8];
#pragma unroll
    for (int i = 0; i < 4; ++i)
#pragma unroll
      for (int j = 0; j < 4; ++j)
        acc[i][j] = MFMA(af[i], bfr[j], acc[i][j]);
    __syncthreads();
  }

  if (MODE == 0 && n0 >= 2048) {
    // V block: store transposed to Vt[dv_global][token], 4 rows packed
#pragma unroll
    for (int i = 0; i < 4; ++i)
#pragma unroll
      for (int j = 0; j < 4; ++j) {
        int col = n0 + wn + j * 16 + r - 2048;
        int row0 = m0 + wm + i * 16 + q * 4;
        unsigned short t4[4];
#pragma unroll
        for (int rg = 0; rg < 4; ++rg) t4[rg] = f2b(acc[i][j][rg]);
        *(uint2*)&Vt[(size_t)col * 8192 + row0] = *(const uint2*)t4;
      }
  } else {
#pragma unroll
    for (int i = 0; i < 4; ++i)
#pragma unroll
      for (int j = 0; j < 4; ++j)
#pragma unroll
        for (int rg = 0; rg < 4; ++rg) {
          int row = m0 + wm + i * 16 + q * 4 + rg;
          int col = n0 + wn + j * 16 + r;
          float v = acc[i][j][rg];
          if (MODE == 0) {
            QK[(size_t)row * 2048 + col] = f2b(v);
          } else {
            v += bias[col] + resid[(size_t)row * N + col];
            Cf[(size_t)row * N + col] = v;
          }
        }
  }
}

// --- flash attention: one block = (h, b, 64 q-rows).
// QK[8192][2048]: cols [0,1024)=Q, [1024,2048)=K (head-major h*64+d).
// Vt[1024][8192]: Vt[h*64+dv][b*2048+key].
__global__ __launch_bounds__(256) void attn_kernel(const unsigned short* __restrict__ QK,
                                                   const unsigned short* __restrict__ Vt,
                                                   unsigned short* __restrict__ O) {
  const int bx = blockIdx.x;
  const int qt = bx & 31, hb = bx >> 5;
  const int h = hb & 15, b = hb >> 4;
  const int tid = threadIdx.x, lane = tid & 63, w = tid >> 6;
  const int r = lane & 15, q = lane >> 4;

  __shared__ __align__(16) unsigned short Ks[64 * PAD];     // [key][d]
  __shared__ __align__(16) unsigned short Vst[64 * PAD];    // [dv][key]
  __shared__ __align__(16) unsigned short Ps[64 * PAD];     // per-wave P

  const size_t RS = 2048;
  const int l0 = qt * 64;

  short8 aq[2];
  {
    const unsigned short* Qr = QK + (size_t)(b * 2048 + l0 + w * 16 + r) * RS + h * 64;
    aq[0] = *(const short8*)&Qr[q * 8];
    aq[1] = *(const short8*)&Qr[32 + q * 8];
  }

  float4v oacc[4] = {};
  float mrow[4], lrow[4];
#pragma unroll
  for (int i = 0; i < 4; ++i) { mrow[i] = -1e30f; lrow[i] = 0.f; }

  for (int kt = 0; kt < 2048; kt += 64) {
    __syncthreads();
    // stage K tile [64][64] -> Ks[key][d], stride PAD
#pragma unroll
    for (int rep = 0; rep < 2; ++rep) {
      int c = tid + rep * 256;
      int row = c >> 3, off = (c & 7) * 8;
      *(uint4*)&Ks[row * PAD + off] =
          *(const uint4*)&QK[(size_t)(b * 2048 + kt + row) * RS + 1024 + h * 64 + off];
    }
    // stage V tile [dv][key] straight from pre-transposed Vt
#pragma unroll
    for (int rep = 0; rep < 2; ++rep) {
      int c = tid + rep * 256;
      int dv = c >> 3, off = (c & 7) * 8;
      *(uint4*)&Vst[dv * PAD + off] =
          *(const uint4*)&Vt[(size_t)(h * 64 + dv) * 8192 + b * 2048 + kt + off];
    }
    __syncthreads();

    // S = (Q K^T) / 32 for this wave's 16 q-rows x 64 keys
    float4v sacc[4];
#pragma unroll
    for (int jn = 0; jn < 4; ++jn) {
      short8 bk0 = *(const short8*)&Ks[(jn * 16 + r) * PAD + q * 8];
      short8 bk1 = *(const short8*)&Ks[(jn * 16 + r) * PAD + 32 + q * 8];
      float4v z = {0.f, 0.f, 0.f, 0.f};
      z = MFMA(aq[0], bk0, z);
      z = MFMA(aq[1], bk1, z);
#pragma unroll
      for (int rg = 0; rg < 4; ++rg) z[rg] *= 0.03125f;
      sacc[jn] = z;
    }

    // online softmax per q-row (row = q*4+rg; 64 cols = 16 lanes x 4 jn)
#pragma unroll
    for (int rg = 0; rg < 4; ++rg) {
      float mx = -1e30f;
#pragma unroll
      for (int jn = 0; jn < 4; ++jn) mx = fmaxf(mx, sacc[jn][rg]);
#pragma unroll
      for (int d = 1; d < 16; d <<= 1) mx = fmaxf(mx, __shfl_xor(mx, d));
      float m_new = fmaxf(mrow[rg], mx);
      float alpha = __expf(mrow[rg] - m_new);
      mrow[rg] = m_new;
      float rs = 0.f;
#pragma unroll
      for (int jn = 0; jn < 4; ++jn) {
        float p = __expf(sacc[jn][rg] - m_new);
        sacc[jn][rg] = p;
        rs += p;
      }
#pragma unroll
      for (int d = 1; d < 16; d <<= 1) rs += __shfl_xor(rs, d);
      lrow[rg] = lrow[rg] * alpha + rs;
#pragma unroll
      for (int jv = 0; jv < 4; ++jv) oacc[jv][rg] *= alpha;
    }

    // P (C-layout) -> LDS -> A-layout (wave-private, no barrier)
#pragma unroll
    for (int jn = 0; jn < 4; ++jn)
#pragma unroll
      for (int rg = 0; rg < 4; ++rg)
        Ps[(w * 16 + q * 4 + rg) * PAD + jn * 16 + r] = f2b(sacc[jn][rg]);
    short8 ap0 = *(const short8*)&Ps[(w * 16 + r) * PAD + q * 8];
    short8 ap1 = *(const short8*)&Ps[(w * 16 + r) * PAD + 32 + q * 8];

    // O += P V
#pragma unroll
    for (int jv = 0; jv < 4; ++jv) {
      short8 bv0 = *(const short8*)&Vst[(jv * 16 + r) * PAD + q * 8];
      short8 bv1 = *(const short8*)&Vst[(jv * 16 + r) * PAD + 32 + q * 8];
      oacc[jv] = MFMA(ap0, bv0, oacc[jv]);
      oacc[jv] = MFMA(ap1, bv1, oacc[jv]);
    }
  }

#pragma unroll
  for (int jv = 0; jv < 4; ++jv)
#pragma unroll
    for (int rg = 0; rg < 4; ++rg) {
      int row = b * 2048 + l0 + w * 16 + q * 4 + rg;
      int col = h * 64 + jv * 16 + r;
      O[(size_t)row * 1024 + col] = f2b(oacc[jv][rg] / lrow[rg]);
    }
}

// --- row LayerNorm: mean, std(ddof=1), /(sigma+1e-3)*a + b  (all fp32)
__global__ __launch_bounds__(256) void ln_kernel(const float* __restrict__ Z,
                                                 const float* __restrict__ ga,
                                                 const float* __restrict__ be,
                                                 float* __restrict__ out) {
  const int row = blockIdx.x;
  const float* z = Z + (size_t)row * 1024;
  const int tid = threadIdx.x;
  float v[4], s = 0.f, sq = 0.f;
#pragma unroll
  for (int i = 0; i < 4; ++i) {
    v[i] = z[tid + i * 256];
    s += v[i];
    sq += v[i] * v[i];
  }
#pragma unroll
  for (int d = 1; d < 64; d <<= 1) { s += __shfl_xor(s, d); sq += __shfl_xor(sq, d); }
  __shared__ float ss[4], ssq[4];
  const int w = tid >> 6, lane = tid & 63;
  if (lane == 0) { ss[w] = s; ssq[w] = sq; }
  __syncthreads();
  s = ss[0] + ss[1] + ss[2] + ss[3];
  sq = ssq[0] + ssq[1] + ssq[2] + ssq[3];
  float mu = s * (1.f / 1024.f);
  float var = fmaxf((sq - 1024.f * mu * mu) * (1.f / 1023.f), 0.f);
  float inv = 1.f / (sqrtf(var) + 1e-3f);
#pragma unroll
  for (int i = 0; i < 4; ++i) {
    int c = tid + i * 256;
    out[(size_t)row * 1024 + c] = (v[i] - mu) * inv * ga[c] + be[c];
  }
}

extern "C" void kernel_launch(void* const* d_in, const int* in_sizes, int n_in,
                              void* d_out, int out_size, void* d_ws, size_t ws_size,
                              hipStream_t stream) {
  (void)in_sizes; (void)n_in; (void)out_size; (void)ws_size;
  const float* q      = (const float*)d_in[0];
  const float* w_qs   = (const float*)d_in[1];
  const float* w_ks   = (const float*)d_in[2];
  const float* w_vs   = (const float*)d_in[3];
  const float* proj_w = (const float*)d_in[4];
  const float* proj_b = (const float*)d_in[5];
  const float* ln_a   = (const float*)d_in[6];
  const float* ln_b   = (const float*)d_in[7];
  float* out = (float*)d_out;

  // ws (88 MB): [Qb 16MB][O 16MB][QK 32MB][Wt 6MB][Pb 2MB][Vt 16MB]
  // Z (fp32, 32MB) aliases QK (dead after attention).
  unsigned short* Qb  = (unsigned short*)d_ws;
  unsigned short* O   = Qb + (size_t)Mrows * Dm;
  unsigned short* QK  = O + (size_t)Mrows * Dm;
  unsigned short* Wt  = QK + (size_t)Mrows * 2048;
  unsigned short* Pb  = Wt + (size_t)NQKV * Dm;
  unsigned short* Vt  = Pb + (size_t)NP_ELEMS;
  float* Z = (float*)QK;

  conv_kernel<<<dim3((NQ_ELEMS + NP_ELEMS) / 256), dim3(256), 0, stream>>>(q, proj_w, Qb, Pb);
  repack_w<<<dim3((3 * 1024 * 1024) / 256), dim3(256), 0, stream>>>(w_qs, w_ks, w_vs, Wt);
  gemm_bt<0><<<dim3(NQKV / 128, Mrows / 128), dim3(256), 0, stream>>>(
      Qb, Wt, QK, Vt, nullptr, nullptr, nullptr, NQKV, Dm);
  attn_kernel<<<dim3(32 * NH * Bb), dim3(256), 0, stream>>>(QK, Vt, O);
  gemm_bt<1><<<dim3(Dm / 128, Mrows / 128), dim3(256), 0, stream>>>(
      O, Pb, nullptr, nullptr, Z, proj_b, q, Dm, Dm);
  ln_kernel<<<dim3(Mrows), dim3(256), 0, stream>>>(Z, ln_a, ln_b, out);
}

// Round 4
// 406.398 us; speedup vs baseline: 1.4865x; 1.1231x over previous
//
#include <hip/hip_runtime.h>
#include <hip/hip_bf16.h>
#include <cstdint>

// ---------------------------------------------------------------------------
// MultiHeadAttention (B=4, L=2048, d_model=1024, 16 heads, d_k=d_v=64)
// Inputs/outputs fp32. Internals: bf16 MFMA, fp32 accum.
// R2: V pre-transposed by QKV-GEMM epilogue; attn LDS stride 72.
// R3: no-max softmax (exp2, Q pre-scaled by log2e/32 in GEMM1 epilogue),
//     deferred row-sum reduction, key-permuted P (b64 writes / b128 reads),
//     32 q-rows per wave (128 per block).
// ---------------------------------------------------------------------------

typedef __attribute__((ext_vector_type(8))) short   short8;
typedef __attribute__((ext_vector_type(8))) __bf16  bf16x8;
typedef __attribute__((ext_vector_type(4))) float   float4v;

template <typename V>
__device__ __forceinline__ auto mfma_sel(V a, V b, float4v c, int)
    -> decltype(__builtin_amdgcn_mfma_f32_16x16x32_bf16(a, b, c, 0, 0, 0)) {
  return __builtin_amdgcn_mfma_f32_16x16x32_bf16(a, b, c, 0, 0, 0);
}
template <typename V>
__device__ __forceinline__ float4v mfma_sel(V a, V b, float4v c, long) {
  return __builtin_amdgcn_mfma_f32_16x16x32_bf16(
      __builtin_bit_cast(bf16x8, a), __builtin_bit_cast(bf16x8, b), c, 0, 0, 0);
}
__device__ __forceinline__ float4v MFMA(short8 a, short8 b, float4v c) {
  return mfma_sel(a, b, c, 0);
}

__device__ __forceinline__ unsigned short f2b(float f) {
  union { float f; unsigned int u; } x; x.f = f;
  unsigned int r = x.u + 0x7FFFu + ((x.u >> 16) & 1u);  // RNE
  return (unsigned short)(r >> 16);
}
__device__ __forceinline__ unsigned int fu(float f) {
  union { float f; unsigned int u; } x; x.f = f; return x.u;
}
__device__ __forceinline__ float fast_exp2(float x) {
#if __has_builtin(__builtin_amdgcn_exp2f)
  return __builtin_amdgcn_exp2f(x);
#else
  return exp2f(x);
#endif
}

constexpr int Bb = 4, Ls = 2048, Dm = 1024, NH = 16;
constexpr int Mrows = Bb * Ls;          // 8192
constexpr int NQKV = 3 * Dm;            // 3072
constexpr int NQ_ELEMS = Mrows * Dm;    // 8388608
constexpr int NP_ELEMS = Dm * Dm;       // 1048576
constexpr int PAD = 72;                 // LDS row stride (halfwords), 144B

// --- fp32 -> bf16 conversion for q (8M) and proj_w (1M)
__global__ __launch_bounds__(256) void conv_kernel(const float* __restrict__ q,
                                                   const float* __restrict__ pw,
                                                   unsigned short* __restrict__ Qb,
                                                   unsigned short* __restrict__ Pb) {
  int idx = blockIdx.x * 256 + threadIdx.x;  // 9437184 total
  if (idx < NQ_ELEMS) Qb[idx] = f2b(q[idx]);
  else                Pb[idx - NQ_ELEMS] = f2b(pw[idx - NQ_ELEMS]);
}

// --- repack fp32 w_qs/w_ks/w_vs [16][1024][64] -> bf16 Wt[3072][1024]
__global__ __launch_bounds__(256) void repack_w(const float* __restrict__ wq,
                                                const float* __restrict__ wk,
                                                const float* __restrict__ wv,
                                                unsigned short* __restrict__ Wt) {
  int idx = blockIdx.x * 256 + threadIdx.x;      // 3*1024*1024 total
  int n = idx >> 10, d = idx & 1023;
  const float* w = (n < 1024) ? wq : (n < 2048 ? wk : wv);
  int nn = n & 1023;
  int h = nn >> 6, kk = nn & 63;
  Wt[idx] = f2b(w[(h * 1024 + d) * 64 + kk]);
}

// --- C = A[M][K] * Bt[N][K]^T (bf16), 128x128 tile, BK=32, 4 waves 64x64
// MODE 0 (QKV): cols<1024 -> Q, scaled by log2e/32; cols in [1024,2048) -> K;
//   both stored bf16 to QK[row*2048+col]. cols>=2048 -> V transposed into
//   Vt[col-2048][row] (uint2 of 4 contiguous rows).
// MODE 1 (proj): +bias(f32) +residual(f32), store fp32 Cf[row*N+col].
template <int MODE>
__global__ __launch_bounds__(256) void gemm_bt(const unsigned short* __restrict__ A,
                                               const unsigned short* __restrict__ Bt,
                                               unsigned short* __restrict__ QK,
                                               unsigned short* __restrict__ Vt,
                                               float* __restrict__ Cf,
                                               const float* __restrict__ bias,
                                               const float* __restrict__ resid,
                                               int N, int K) {
  __shared__ __align__(16) unsigned short As[128 * 32];
  __shared__ __align__(16) unsigned short Bs[128 * 32];
  const int tid = threadIdx.x;
  const int lane = tid & 63, w = tid >> 6;
  const int wm = (w >> 1) * 64, wn = (w & 1) * 64;
  const int m0 = blockIdx.y * 128, n0 = blockIdx.x * 128;
  const int r = lane & 15, q = lane >> 4;

  float4v acc[4][4] = {};

  for (int k0 = 0; k0 < K; k0 += 32) {
#pragma unroll
    for (int rep = 0; rep < 2; ++rep) {
      int c = tid + rep * 256;               // 512 chunks of 8 bf16
      int row = c >> 2, col = (c & 3) * 8;
      *(uint4*)&As[row * 32 + col] = *(const uint4*)&A[(size_t)(m0 + row) * K + k0 + col];
      *(uint4*)&Bs[row * 32 + col] = *(const uint4*)&Bt[(size_t)(n0 + row) * K + k0 + col];
    }
    __syncthreads();
    short8 af[4], bfr[4];
#pragma unroll
    for (int i = 0; i < 4; ++i)
      af[i] = *(const short8*)&As[(wm + i * 16 + r) * 32 + q * 8];
#pragma unroll
    for (int j = 0; j < 4; ++j)
      bfr[j] = *(const short8*)&Bs[(wn + j * 16 + r) * 32 + q * 8];
#pragma unroll
    for (int i = 0; i < 4; ++i)
#pragma unroll
      for (int j = 0; j < 4; ++j)
        acc[i][j] = MFMA(af[i], bfr[j], acc[i][j]);
    __syncthreads();
  }

  if (MODE == 0 && n0 >= 2048) {
    // V block: store transposed to Vt[dv_global][token], 4 rows packed
#pragma unroll
    for (int i = 0; i < 4; ++i)
#pragma unroll
      for (int j = 0; j < 4; ++j) {
        int col = n0 + wn + j * 16 + r - 2048;
        int row0 = m0 + wm + i * 16 + q * 4;
        unsigned short t4[4];
#pragma unroll
        for (int rg = 0; rg < 4; ++rg) t4[rg] = f2b(acc[i][j][rg]);
        *(uint2*)&Vt[(size_t)col * 8192 + row0] = *(const uint2*)t4;
      }
  } else {
    const float qscale = (MODE == 0 && n0 < 1024) ? 0.045084230f /*log2e/32*/ : 1.0f;
#pragma unroll
    for (int i = 0; i < 4; ++i)
#pragma unroll
      for (int j = 0; j < 4; ++j)
#pragma unroll
        for (int rg = 0; rg < 4; ++rg) {
          int row = m0 + wm + i * 16 + q * 4 + rg;
          int col = n0 + wn + j * 16 + r;
          float v = acc[i][j][rg];
          if (MODE == 0) {
            QK[(size_t)row * 2048 + col] = f2b(v * qscale);
          } else {
            v += bias[col] + resid[(size_t)row * N + col];
            Cf[(size_t)row * N + col] = v;
          }
        }
  }
}

// --- flash attention (no-max softmax): one block = (h, b, 128 q-rows),
// 4 waves x 32 rows. QK[8192][2048]: cols [0,1024)=Q (pre-scaled by
// log2e/32), [1024,2048)=K. Vt[1024][8192]: Vt[h*64+dv][b*2048+key].
// Key permutation pi(key=16*jn+r) = 4*r+jn applied to P cols AND V rows
// (PV invariant): P writes become b64, P A-frags read as direct b128.
__global__ __launch_bounds__(256) void attn_kernel(const unsigned short* __restrict__ QK,
                                                   const unsigned short* __restrict__ Vt,
                                                   unsigned short* __restrict__ O) {
  const int bx = blockIdx.x;
  const int qt = bx & 15, hb = bx >> 4;
  const int h = hb & 15, b = hb >> 4;
  const int tid = threadIdx.x, lane = tid & 63, w = tid >> 6;
  const int r = lane & 15, q = lane >> 4;

  __shared__ __align__(16) unsigned short Ks[64 * PAD];    // [key][d]
  __shared__ __align__(16) unsigned short Vst[64 * PAD];   // [dv][key]
  __shared__ __align__(16) unsigned short Ps[128 * PAD];   // [qrow][pi(key)] bf16

  const size_t RS = 2048;
  const int l0 = qt * 128;

  short8 aq[2][2];
#pragma unroll
  for (int i = 0; i < 2; ++i) {
    const unsigned short* Qr =
        QK + (size_t)(b * 2048 + l0 + w * 32 + i * 16 + r) * RS + h * 64;
    aq[i][0] = *(const short8*)&Qr[q * 8];
    aq[i][1] = *(const short8*)&Qr[32 + q * 8];
  }

  float4v oacc[2][4] = {};
  float lsum[8] = {};

  for (int kt = 0; kt < 2048; kt += 64) {
    __syncthreads();
    // stage K tile [64][64] -> Ks[key][d], stride PAD
#pragma unroll
    for (int rep = 0; rep < 2; ++rep) {
      int c = tid + rep * 256;
      int row = c >> 3, off = (c & 7) * 8;
      *(uint4*)&Ks[row * PAD + off] =
          *(const uint4*)&QK[(size_t)(b * 2048 + kt + row) * RS + 1024 + h * 64 + off];
    }
    // stage V tile [dv][key] straight from pre-transposed Vt
#pragma unroll
    for (int rep = 0; rep < 2; ++rep) {
      int c = tid + rep * 256;
      int dv = c >> 3, off = (c & 7) * 8;
      *(uint4*)&Vst[dv * PAD + off] =
          *(const uint4*)&Vt[(size_t)(h * 64 + dv) * 8192 + b * 2048 + kt + off];
    }
    __syncthreads();

    // K fragments (shared across both i row-blocks)
    short8 bk[4][2];
#pragma unroll
    for (int jn = 0; jn < 4; ++jn) {
      bk[jn][0] = *(const short8*)&Ks[(jn * 16 + r) * PAD + q * 8];
      bk[jn][1] = *(const short8*)&Ks[(jn * 16 + r) * PAD + 32 + q * 8];
    }

    // S = Q K^T (pre-scaled); exp2; accumulate lsum; pack P to LDS (pi order)
#pragma unroll
    for (int i = 0; i < 2; ++i) {
      float4v sacc[4];
#pragma unroll
      for (int jn = 0; jn < 4; ++jn) {
        float4v z = {0.f, 0.f, 0.f, 0.f};
        z = MFMA(aq[i][0], bk[jn][0], z);
        z = MFMA(aq[i][1], bk[jn][1], z);
        sacc[jn] = z;
      }
#pragma unroll
      for (int rg = 0; rg < 4; ++rg) {
        float p0 = fast_exp2(sacc[0][rg]);
        float p1 = fast_exp2(sacc[1][rg]);
        float p2 = fast_exp2(sacc[2][rg]);
        float p3 = fast_exp2(sacc[3][rg]);
        lsum[i * 4 + rg] += (p0 + p1) + (p2 + p3);
        // truncating bf16 pack: halfwords [pi=4r+0..3] = (p0,p1,p2,p3)
        uint2 pk;
        pk.x = __builtin_amdgcn_perm(fu(p1), fu(p0), 0x07060302u);
        pk.y = __builtin_amdgcn_perm(fu(p3), fu(p2), 0x07060302u);
        *(uint2*)&Ps[(w * 32 + i * 16 + q * 4 + rg) * PAD + r * 4] = pk;
      }
    }

    // V fragments in pi order: frag elem j <-> key 16*(j%4) + 8*kh + 2q + j/4
    short8 bv[4][2];
#pragma unroll
    for (int jv = 0; jv < 4; ++jv) {
      const int dv = jv * 16 + r;
#pragma unroll
      for (int kh = 0; kh < 2; ++kh) {
        unsigned int L0 = *(const unsigned int*)&Vst[dv * PAD + 0  + 8 * kh + 2 * q];
        unsigned int L1 = *(const unsigned int*)&Vst[dv * PAD + 16 + 8 * kh + 2 * q];
        unsigned int L2 = *(const unsigned int*)&Vst[dv * PAD + 32 + 8 * kh + 2 * q];
        unsigned int L3 = *(const unsigned int*)&Vst[dv * PAD + 48 + 8 * kh + 2 * q];
        unsigned int u0 = __builtin_amdgcn_perm(L1, L0, 0x05040100u);  // (k16,k0) lo
        unsigned int u1 = __builtin_amdgcn_perm(L3, L2, 0x05040100u);
        unsigned int u2 = __builtin_amdgcn_perm(L1, L0, 0x07060302u);  // (k17,k1) hi
        unsigned int u3 = __builtin_amdgcn_perm(L3, L2, 0x07060302u);
        uint4 fr = {u0, u1, u2, u3};
        bv[jv][kh] = __builtin_bit_cast(short8, fr);
      }
    }

    // O += P V  (P A-frags are direct b128 reads in pi order)
#pragma unroll
    for (int i = 0; i < 2; ++i) {
      short8 ap0 = *(const short8*)&Ps[(w * 32 + i * 16 + r) * PAD + q * 8];
      short8 ap1 = *(const short8*)&Ps[(w * 32 + i * 16 + r) * PAD + 32 + q * 8];
#pragma unroll
      for (int jv = 0; jv < 4; ++jv) {
        oacc[i][jv] = MFMA(ap0, bv[jv][0], oacc[i][jv]);
        oacc[i][jv] = MFMA(ap1, bv[jv][1], oacc[i][jv]);
      }
    }
  }

  // one-time row-sum reduction across the 16 r-lanes
#pragma unroll
  for (int t = 0; t < 8; ++t)
#pragma unroll
    for (int d = 1; d < 16; d <<= 1) lsum[t] += __shfl_xor(lsum[t], d);

#pragma unroll
  for (int i = 0; i < 2; ++i)
#pragma unroll
    for (int jv = 0; jv < 4; ++jv)
#pragma unroll
      for (int rg = 0; rg < 4; ++rg) {
        int row = b * 2048 + l0 + w * 32 + i * 16 + q * 4 + rg;
        int col = h * 64 + jv * 16 + r;
        O[(size_t)row * 1024 + col] = f2b(oacc[i][jv][rg] / lsum[i * 4 + rg]);
      }
}

// --- row LayerNorm: mean, std(ddof=1), /(sigma+1e-3)*a + b  (all fp32)
__global__ __launch_bounds__(256) void ln_kernel(const float* __restrict__ Z,
                                                 const float* __restrict__ ga,
                                                 const float* __restrict__ be,
                                                 float* __restrict__ out) {
  const int row = blockIdx.x;
  const float* z = Z + (size_t)row * 1024;
  const int tid = threadIdx.x;
  float v[4], s = 0.f, sq = 0.f;
#pragma unroll
  for (int i = 0; i < 4; ++i) {
    v[i] = z[tid + i * 256];
    s += v[i];
    sq += v[i] * v[i];
  }
#pragma unroll
  for (int d = 1; d < 64; d <<= 1) { s += __shfl_xor(s, d); sq += __shfl_xor(sq, d); }
  __shared__ float ss[4], ssq[4];
  const int w = tid >> 6, lane = tid & 63;
  if (lane == 0) { ss[w] = s; ssq[w] = sq; }
  __syncthreads();
  s = ss[0] + ss[1] + ss[2] + ss[3];
  sq = ssq[0] + ssq[1] + ssq[2] + ssq[3];
  float mu = s * (1.f / 1024.f);
  float var = fmaxf((sq - 1024.f * mu * mu) * (1.f / 1023.f), 0.f);
  float inv = 1.f / (sqrtf(var) + 1e-3f);
#pragma unroll
  for (int i = 0; i < 4; ++i) {
    int c = tid + i * 256;
    out[(size_t)row * 1024 + c] = (v[i] - mu) * inv * ga[c] + be[c];
  }
}

extern "C" void kernel_launch(void* const* d_in, const int* in_sizes, int n_in,
                              void* d_out, int out_size, void* d_ws, size_t ws_size,
                              hipStream_t stream) {
  (void)in_sizes; (void)n_in; (void)out_size; (void)ws_size;
  const float* q      = (const float*)d_in[0];
  const float* w_qs   = (const float*)d_in[1];
  const float* w_ks   = (const float*)d_in[2];
  const float* w_vs   = (const float*)d_in[3];
  const float* proj_w = (const float*)d_in[4];
  const float* proj_b = (const float*)d_in[5];
  const float* ln_a   = (const float*)d_in[6];
  const float* ln_b   = (const float*)d_in[7];
  float* out = (float*)d_out;

  // ws (88 MB): [Qb 16MB][O 16MB][QK 32MB][Wt 6MB][Pb 2MB][Vt 16MB]
  // Z (fp32, 32MB) aliases QK (dead after attention).
  unsigned short* Qb  = (unsigned short*)d_ws;
  unsigned short* O   = Qb + (size_t)Mrows * Dm;
  unsigned short* QK  = O + (size_t)Mrows * Dm;
  unsigned short* Wt  = QK + (size_t)Mrows * 2048;
  unsigned short* Pb  = Wt + (size_t)NQKV * Dm;
  unsigned short* Vt  = Pb + (size_t)NP_ELEMS;
  float* Z = (float*)QK;

  conv_kernel<<<dim3((NQ_ELEMS + NP_ELEMS) / 256), dim3(256), 0, stream>>>(q, proj_w, Qb, Pb);
  repack_w<<<dim3((3 * 1024 * 1024) / 256), dim3(256), 0, stream>>>(w_qs, w_ks, w_vs, Wt);
  gemm_bt<0><<<dim3(NQKV / 128, Mrows / 128), dim3(256), 0, stream>>>(
      Qb, Wt, QK, Vt, nullptr, nullptr, nullptr, NQKV, Dm);
  attn_kernel<<<dim3(16 * NH * Bb), dim3(256), 0, stream>>>(QK, Vt, O);
  gemm_bt<1><<<dim3(Dm / 128, Mrows / 128), dim3(256), 0, stream>>>(
      O, Pb, nullptr, nullptr, Z, proj_b, q, Dm, Dm);
  ln_kernel<<<dim3(Mrows), dim3(256), 0, stream>>>(Z, ln_a, ln_b, out);
}

// Round 5
// 386.516 us; speedup vs baseline: 1.5629x; 1.0514x over previous
//
#include <hip/hip_runtime.h>
#include <hip/hip_bf16.h>
#include <cstdint>

// ---------------------------------------------------------------------------
// MultiHeadAttention (B=4, L=2048, d_model=1024, 16 heads, d_k=d_v=64)
// Inputs/outputs fp32. Internals: bf16 MFMA, fp32 accum.
// R2: V pre-transposed by QKV-GEMM epilogue; attn LDS stride 72.
// R3: no-max softmax (exp2, Q pre-scaled by log2e/32), deferred row-sum,
//     key-permuted P, 32 q-rows per wave.
// R4: pi-permutation moved into global Vt (GEMM epilogue stores pi-ordered,
//     attention bv = direct b128 reads); GEMMs use global_load_lds width-16.
// ---------------------------------------------------------------------------

typedef __attribute__((ext_vector_type(8))) short   short8;
typedef __attribute__((ext_vector_type(8))) __bf16  bf16x8;
typedef __attribute__((ext_vector_type(4))) float   float4v;

template <typename V>
__device__ __forceinline__ auto mfma_sel(V a, V b, float4v c, int)
    -> decltype(__builtin_amdgcn_mfma_f32_16x16x32_bf16(a, b, c, 0, 0, 0)) {
  return __builtin_amdgcn_mfma_f32_16x16x32_bf16(a, b, c, 0, 0, 0);
}
template <typename V>
__device__ __forceinline__ float4v mfma_sel(V a, V b, float4v c, long) {
  return __builtin_amdgcn_mfma_f32_16x16x32_bf16(
      __builtin_bit_cast(bf16x8, a), __builtin_bit_cast(bf16x8, b), c, 0, 0, 0);
}
__device__ __forceinline__ float4v MFMA(short8 a, short8 b, float4v c) {
  return mfma_sel(a, b, c, 0);
}

__device__ __forceinline__ unsigned short f2b(float f) {
  union { float f; unsigned int u; } x; x.f = f;
  unsigned int r = x.u + 0x7FFFu + ((x.u >> 16) & 1u);  // RNE
  return (unsigned short)(r >> 16);
}
__device__ __forceinline__ unsigned int fu(float f) {
  union { float f; unsigned int u; } x; x.f = f; return x.u;
}
__device__ __forceinline__ float fast_exp2(float x) {
#if __has_builtin(__builtin_amdgcn_exp2f)
  return __builtin_amdgcn_exp2f(x);
#else
  return exp2f(x);
#endif
}

// async global->LDS, 16B per lane; LDS dest = wave-uniform base + lane*16
__device__ __forceinline__ void async_cp16(const unsigned short* g, unsigned short* l) {
  __builtin_amdgcn_global_load_lds(
      (const __attribute__((address_space(1))) void*)g,
      (__attribute__((address_space(3))) void*)l, 16, 0, 0);
}

constexpr int Bb = 4, Ls = 2048, Dm = 1024, NH = 16;
constexpr int Mrows = Bb * Ls;          // 8192
constexpr int NQKV = 3 * Dm;            // 3072
constexpr int NQ_ELEMS = Mrows * Dm;    // 8388608
constexpr int NP_ELEMS = Dm * Dm;       // 1048576
constexpr int PAD = 72;                 // LDS row stride (halfwords), 144B

// --- fp32 -> bf16 conversion for q (8M) and proj_w (1M)
__global__ __launch_bounds__(256) void conv_kernel(const float* __restrict__ q,
                                                   const float* __restrict__ pw,
                                                   unsigned short* __restrict__ Qb,
                                                   unsigned short* __restrict__ Pb) {
  int idx = blockIdx.x * 256 + threadIdx.x;  // 9437184 total
  if (idx < NQ_ELEMS) Qb[idx] = f2b(q[idx]);
  else                Pb[idx - NQ_ELEMS] = f2b(pw[idx - NQ_ELEMS]);
}

// --- repack fp32 w_qs/w_ks/w_vs [16][1024][64] -> bf16 Wt[3072][1024]
__global__ __launch_bounds__(256) void repack_w(const float* __restrict__ wq,
                                                const float* __restrict__ wk,
                                                const float* __restrict__ wv,
                                                unsigned short* __restrict__ Wt) {
  int idx = blockIdx.x * 256 + threadIdx.x;      // 3*1024*1024 total
  int n = idx >> 10, d = idx & 1023;
  const float* w = (n < 1024) ? wq : (n < 2048 ? wk : wv);
  int nn = n & 1023;
  int h = nn >> 6, kk = nn & 63;
  Wt[idx] = f2b(w[(h * 1024 + d) * 64 + kk]);
}

// --- C = A[M][K] * Bt[N][K]^T (bf16), 128x128 tile, BK=32, 4 waves 64x64,
// async global_load_lds width-16 staging.
// MODE 0 (QKV): cols<1024 -> Q scaled by log2e/32 -> QK; [1024,2048) -> K
//   -> QK. cols>=2048 -> V stored pi-ordered into Vt[dv][8192]:
//   Vt[dv][64*(t/64) + pi(t%64)], pi(16*jn+r) = 4*r+jn. Each lane holds the
//   16 values for 16 contiguous pi-positions [16q,16q+16): p=16q+4*rg+i.
// MODE 1 (proj): +bias(f32) +residual(f32), store fp32 Cf[row*N+col].
template <int MODE>
__global__ __launch_bounds__(256) void gemm_bt(const unsigned short* __restrict__ A,
                                               const unsigned short* __restrict__ Bt,
                                               unsigned short* __restrict__ QK,
                                               unsigned short* __restrict__ Vt,
                                               float* __restrict__ Cf,
                                               const float* __restrict__ bias,
                                               const float* __restrict__ resid,
                                               int N, int K) {
  __shared__ __align__(16) unsigned short As[128 * 32];
  __shared__ __align__(16) unsigned short Bs[128 * 32];
  const int tid = threadIdx.x;
  const int lane = tid & 63, w = tid >> 6;
  const int wm = (w >> 1) * 64, wn = (w & 1) * 64;
  const int m0 = blockIdx.y * 128, n0 = blockIdx.x * 128;
  const int r = lane & 15, q = lane >> 4;

  // staging maps: issue covers 64 rows; wave w covers rows 16w..16w+16
  const unsigned short* gA = A + (size_t)(m0 + 16 * w + (lane >> 2)) * K + (lane & 3) * 8;
  const unsigned short* gB = Bt + (size_t)(n0 + 16 * w + (lane >> 2)) * K + (lane & 3) * 8;
  unsigned short* lA0 = As + 16 * w * 32;
  unsigned short* lA1 = As + (64 + 16 * w) * 32;
  unsigned short* lB0 = Bs + 16 * w * 32;
  unsigned short* lB1 = Bs + (64 + 16 * w) * 32;

  float4v acc[4][4] = {};

  for (int k0 = 0; k0 < K; k0 += 32) {
    async_cp16(gA + k0, lA0);
    async_cp16(gA + (size_t)64 * K + k0, lA1);
    async_cp16(gB + k0, lB0);
    async_cp16(gB + (size_t)64 * K + k0, lB1);
    __syncthreads();
    short8 af[4], bfr[4];
#pragma unroll
    for (int i = 0; i < 4; ++i)
      af[i] = *(const short8*)&As[(wm + i * 16 + r) * 32 + q * 8];
#pragma unroll
    for (int j = 0; j < 4; ++j)
      bfr[j] = *(const short8*)&Bs[(wn + j * 16 + r) * 32 + q * 8];
#pragma unroll
    for (int i = 0; i < 4; ++i)
#pragma unroll
      for (int j = 0; j < 4; ++j)
        acc[i][j] = MFMA(af[i], bfr[j], acc[i][j]);
    __syncthreads();
  }

  if (MODE == 0 && n0 >= 2048) {
    // pi-ordered V: lane writes positions [16q, 16q+16) of token-tile m0+wm
#pragma unroll
    for (int j = 0; j < 4; ++j) {
      int dv = n0 + wn + j * 16 + r - 2048;
      unsigned short t16[16];
#pragma unroll
      for (int i = 0; i < 4; ++i)
#pragma unroll
        for (int rg = 0; rg < 4; ++rg)
          t16[4 * rg + i] = f2b(acc[i][j][rg]);
      unsigned short* dst = Vt + (size_t)dv * 8192 + (m0 + wm) + 16 * q;
      *(uint4*)&dst[0] = *(const uint4*)&t16[0];
      *(uint4*)&dst[8] = *(const uint4*)&t16[8];
    }
  } else {
    const float qscale = (MODE == 0 && n0 < 1024) ? 0.045084230f /*log2e/32*/ : 1.0f;
#pragma unroll
    for (int i = 0; i < 4; ++i)
#pragma unroll
      for (int j = 0; j < 4; ++j)
#pragma unroll
        for (int rg = 0; rg < 4; ++rg) {
          int row = m0 + wm + i * 16 + q * 4 + rg;
          int col = n0 + wn + j * 16 + r;
          float v = acc[i][j][rg];
          if (MODE == 0) {
            QK[(size_t)row * 2048 + col] = f2b(v * qscale);
          } else {
            v += bias[col] + resid[(size_t)row * N + col];
            Cf[(size_t)row * N + col] = v;
          }
        }
  }
}

// --- flash attention (no-max softmax): one block = (h, b, 128 q-rows),
// 4 waves x 32 rows. QK[8192][2048]: cols [0,1024)=Q (pre-scaled by
// log2e/32), [1024,2048)=K. Vt[1024][8192] pi-ordered per 64-token tile.
// P stored to LDS at pi(key)=4r+jn (b64 writes); both P A-frags and V
// B-frags are direct b128 reads in pi order.
__global__ __launch_bounds__(256) void attn_kernel(const unsigned short* __restrict__ QK,
                                                   const unsigned short* __restrict__ Vt,
                                                   unsigned short* __restrict__ O) {
  const int bx = blockIdx.x;
  const int qt = bx & 15, hb = bx >> 4;
  const int h = hb & 15, b = hb >> 4;
  const int tid = threadIdx.x, lane = tid & 63, w = tid >> 6;
  const int r = lane & 15, q = lane >> 4;

  __shared__ __align__(16) unsigned short Ks[64 * PAD];    // [key][d]
  __shared__ __align__(16) unsigned short Vst[64 * PAD];   // [dv][pi(key)]
  __shared__ __align__(16) unsigned short Ps[128 * PAD];   // [qrow][pi(key)]

  const size_t RS = 2048;
  const int l0 = qt * 128;

  short8 aq[2][2];
#pragma unroll
  for (int i = 0; i < 2; ++i) {
    const unsigned short* Qr =
        QK + (size_t)(b * 2048 + l0 + w * 32 + i * 16 + r) * RS + h * 64;
    aq[i][0] = *(const short8*)&Qr[q * 8];
    aq[i][1] = *(const short8*)&Qr[32 + q * 8];
  }

  float4v oacc[2][4] = {};
  float lsum[8] = {};

  for (int kt = 0; kt < 2048; kt += 64) {
    __syncthreads();
    // stage K tile [64][64] -> Ks[key][d], stride PAD
#pragma unroll
    for (int rep = 0; rep < 2; ++rep) {
      int c = tid + rep * 256;
      int row = c >> 3, off = (c & 7) * 8;
      *(uint4*)&Ks[row * PAD + off] =
          *(const uint4*)&QK[(size_t)(b * 2048 + kt + row) * RS + 1024 + h * 64 + off];
    }
    // stage V tile [dv][pi(key)] straight from pi-ordered Vt
#pragma unroll
    for (int rep = 0; rep < 2; ++rep) {
      int c = tid + rep * 256;
      int dv = c >> 3, off = (c & 7) * 8;
      *(uint4*)&Vst[dv * PAD + off] =
          *(const uint4*)&Vt[(size_t)(h * 64 + dv) * 8192 + b * 2048 + kt + off];
    }
    __syncthreads();

    // K fragments (shared across both i row-blocks)
    short8 bk[4][2];
#pragma unroll
    for (int jn = 0; jn < 4; ++jn) {
      bk[jn][0] = *(const short8*)&Ks[(jn * 16 + r) * PAD + q * 8];
      bk[jn][1] = *(const short8*)&Ks[(jn * 16 + r) * PAD + 32 + q * 8];
    }

    // S = Q K^T (pre-scaled); exp2; accumulate lsum; pack P to LDS (pi order)
#pragma unroll
    for (int i = 0; i < 2; ++i) {
      float4v sacc[4];
#pragma unroll
      for (int jn = 0; jn < 4; ++jn) {
        float4v z = {0.f, 0.f, 0.f, 0.f};
        z = MFMA(aq[i][0], bk[jn][0], z);
        z = MFMA(aq[i][1], bk[jn][1], z);
        sacc[jn] = z;
      }
#pragma unroll
      for (int rg = 0; rg < 4; ++rg) {
        float p0 = fast_exp2(sacc[0][rg]);
        float p1 = fast_exp2(sacc[1][rg]);
        float p2 = fast_exp2(sacc[2][rg]);
        float p3 = fast_exp2(sacc[3][rg]);
        lsum[i * 4 + rg] += (p0 + p1) + (p2 + p3);
        // truncating bf16 pack: halfwords [pi=4r+0..3] = (p0,p1,p2,p3)
        uint2 pk;
        pk.x = __builtin_amdgcn_perm(fu(p1), fu(p0), 0x07060302u);
        pk.y = __builtin_amdgcn_perm(fu(p3), fu(p2), 0x07060302u);
        *(uint2*)&Ps[(w * 32 + i * 16 + q * 4 + rg) * PAD + r * 4] = pk;
      }
    }

    // V fragments: direct b128 reads (Vst already pi-ordered)
    short8 bv[4][2];
#pragma unroll
    for (int jv = 0; jv < 4; ++jv) {
      bv[jv][0] = *(const short8*)&Vst[(jv * 16 + r) * PAD + q * 8];
      bv[jv][1] = *(const short8*)&Vst[(jv * 16 + r) * PAD + 32 + q * 8];
    }

    // O += P V  (P A-frags are direct b128 reads in pi order)
#pragma unroll
    for (int i = 0; i < 2; ++i) {
      short8 ap0 = *(const short8*)&Ps[(w * 32 + i * 16 + r) * PAD + q * 8];
      short8 ap1 = *(const short8*)&Ps[(w * 32 + i * 16 + r) * PAD + 32 + q * 8];
#pragma unroll
      for (int jv = 0; jv < 4; ++jv) {
        oacc[i][jv] = MFMA(ap0, bv[jv][0], oacc[i][jv]);
        oacc[i][jv] = MFMA(ap1, bv[jv][1], oacc[i][jv]);
      }
    }
  }

  // one-time row-sum reduction across the 16 r-lanes
#pragma unroll
  for (int t = 0; t < 8; ++t)
#pragma unroll
    for (int d = 1; d < 16; d <<= 1) lsum[t] += __shfl_xor(lsum[t], d);

#pragma unroll
  for (int i = 0; i < 2; ++i)
#pragma unroll
    for (int jv = 0; jv < 4; ++jv)
#pragma unroll
      for (int rg = 0; rg < 4; ++rg) {
        int row = b * 2048 + l0 + w * 32 + i * 16 + q * 4 + rg;
        int col = h * 64 + jv * 16 + r;
        O[(size_t)row * 1024 + col] = f2b(oacc[i][jv][rg] / lsum[i * 4 + rg]);
      }
}

// --- row LayerNorm: mean, std(ddof=1), /(sigma+1e-3)*a + b  (all fp32)
__global__ __launch_bounds__(256) void ln_kernel(const float* __restrict__ Z,
                                                 const float* __restrict__ ga,
                                                 const float* __restrict__ be,
                                                 float* __restrict__ out) {
  const int row = blockIdx.x;
  const float* z = Z + (size_t)row * 1024;
  const int tid = threadIdx.x;
  float v[4], s = 0.f, sq = 0.f;
#pragma unroll
  for (int i = 0; i < 4; ++i) {
    v[i] = z[tid + i * 256];
    s += v[i];
    sq += v[i] * v[i];
  }
#pragma unroll
  for (int d = 1; d < 64; d <<= 1) { s += __shfl_xor(s, d); sq += __shfl_xor(sq, d); }
  __shared__ float ss[4], ssq[4];
  const int w = tid >> 6, lane = tid & 63;
  if (lane == 0) { ss[w] = s; ssq[w] = sq; }
  __syncthreads();
  s = ss[0] + ss[1] + ss[2] + ss[3];
  sq = ssq[0] + ssq[1] + ssq[2] + ssq[3];
  float mu = s * (1.f / 1024.f);
  float var = fmaxf((sq - 1024.f * mu * mu) * (1.f / 1023.f), 0.f);
  float inv = 1.f / (sqrtf(var) + 1e-3f);
#pragma unroll
  for (int i = 0; i < 4; ++i) {
    int c = tid + i * 256;
    out[(size_t)row * 1024 + c] = (v[i] - mu) * inv * ga[c] + be[c];
  }
}

extern "C" void kernel_launch(void* const* d_in, const int* in_sizes, int n_in,
                              void* d_out, int out_size, void* d_ws, size_t ws_size,
                              hipStream_t stream) {
  (void)in_sizes; (void)n_in; (void)out_size; (void)ws_size;
  const float* q      = (const float*)d_in[0];
  const float* w_qs   = (const float*)d_in[1];
  const float* w_ks   = (const float*)d_in[2];
  const float* w_vs   = (const float*)d_in[3];
  const float* proj_w = (const float*)d_in[4];
  const float* proj_b = (const float*)d_in[5];
  const float* ln_a   = (const float*)d_in[6];
  const float* ln_b   = (const float*)d_in[7];
  float* out = (float*)d_out;

  // ws (88 MB): [Qb 16MB][O 16MB][QK 32MB][Wt 6MB][Pb 2MB][Vt 16MB]
  // Z (fp32, 32MB) aliases QK (dead after attention).
  unsigned short* Qb  = (unsigned short*)d_ws;
  unsigned short* O   = Qb + (size_t)Mrows * Dm;
  unsigned short* QK  = O + (size_t)Mrows * Dm;
  unsigned short* Wt  = QK + (size_t)Mrows * 2048;
  unsigned short* Pb  = Wt + (size_t)NQKV * Dm;
  unsigned short* Vt  = Pb + (size_t)NP_ELEMS;
  float* Z = (float*)QK;

  conv_kernel<<<dim3((NQ_ELEMS + NP_ELEMS) / 256), dim3(256), 0, stream>>>(q, proj_w, Qb, Pb);
  repack_w<<<dim3((3 * 1024 * 1024) / 256), dim3(256), 0, stream>>>(w_qs, w_ks, w_vs, Wt);
  gemm_bt<0><<<dim3(NQKV / 128, Mrows / 128), dim3(256), 0, stream>>>(
      Qb, Wt, QK, Vt, nullptr, nullptr, nullptr, NQKV, Dm);
  attn_kernel<<<dim3(16 * NH * Bb), dim3(256), 0, stream>>>(QK, Vt, O);
  gemm_bt<1><<<dim3(Dm / 128, Mrows / 128), dim3(256), 0, stream>>>(
      O, Pb, nullptr, nullptr, Z, proj_b, q, Dm, Dm);
  ln_kernel<<<dim3(Mrows), dim3(256), 0, stream>>>(Z, ln_a, ln_b, out);
}